// Round 6
// baseline (219.188 us; speedup 1.0000x reference)
//
#include <hip/hip_runtime.h>
#include <math.h>

// Problem: B=4, S=1024, F=256, H=8, FH=2048. SCALE=16 (multiplies logits).
#define SQ 1024
#define FQ 256
#define FH 2048

typedef _Float16 f16;
typedef f16  f16x8 __attribute__((ext_vector_type(8)));
typedef float f32x4 __attribute__((ext_vector_type(4)));

// Async global->LDS, 16 B/lane. LDS dest = wave-uniform base + lane*16.
#define GLOAD_LDS16(gp, lp) \
    __builtin_amdgcn_global_load_lds((const __attribute__((address_space(1))) void*)(gp), \
                                     (__attribute__((address_space(3))) void*)(lp), 16, 0, 0)

// ---------------------------------------------------------------------------
// fp32 -> f16 convert (x input).
// ---------------------------------------------------------------------------
__global__ __launch_bounds__(256) void cvt_kernel(const float* __restrict__ in,
                                                  f16* __restrict__ out) {
    int idx = (blockIdx.x * 256 + threadIdx.x) * 4;
    float4 v = *(const float4*)(in + idx);
    out[idx + 0] = (f16)v.x; out[idx + 1] = (f16)v.y;
    out[idx + 2] = (f16)v.z; out[idx + 3] = (f16)v.w;
}

// ---------------------------------------------------------------------------
// Transpose+convert W (256 x 2048 fp32) -> WT (2048 x 256 f16). z picks matrix.
// ---------------------------------------------------------------------------
__global__ __launch_bounds__(256) void transpose_qkv(const float* __restrict__ W0,
                                                     const float* __restrict__ W1,
                                                     const float* __restrict__ W2,
                                                     f16* __restrict__ T0,
                                                     f16* __restrict__ T1,
                                                     f16* __restrict__ T2) {
    const float* W = blockIdx.z == 0 ? W0 : (blockIdx.z == 1 ? W1 : W2);
    f16* WT        = blockIdx.z == 0 ? T0 : (blockIdx.z == 1 ? T1 : T2);
    __shared__ f16 T[32][33];
    const int tx = threadIdx.x & 31, ty = threadIdx.x >> 5;
    const int n0 = blockIdx.x * 32, k0 = blockIdx.y * 32;
#pragma unroll
    for (int i = 0; i < 4; ++i)
        T[ty + i * 8][tx] = (f16)W[(size_t)(k0 + ty + i * 8) * FH + n0 + tx];
    __syncthreads();
#pragma unroll
    for (int i = 0; i < 4; ++i)
        WT[(size_t)(n0 + ty + i * 8) * FQ + k0 + tx] = T[tx][ty + i * 8];
}

// ---------------------------------------------------------------------------
// Wo (2048 x 256 fp32, row fh = f*8+h) -> WoT (256 x 2048 f16) with k
// PERMUTED to h*256+f (matches WV layout). grid (8 n-tiles, 64 = ft*8+h).
// ---------------------------------------------------------------------------
__global__ __launch_bounds__(256) void transpose_wo(const float* __restrict__ W,
                                                    f16* __restrict__ WT) {
    __shared__ f16 T[32][33];
    const int tx = threadIdx.x & 31, ty = threadIdx.x >> 5;
    const int n0 = blockIdx.x * 32;
    const int ft = blockIdx.y >> 3, h = blockIdx.y & 7;
#pragma unroll
    for (int i = 0; i < 4; ++i) {
        int fl = ty + i * 8;
        T[fl][tx] = (f16)W[(size_t)((ft * 32 + fl) * 8 + h) * FQ + n0 + tx];
    }
    __syncthreads();
#pragma unroll
    for (int i = 0; i < 4; ++i)
        WT[(size_t)(n0 + ty + i * 8) * FH + h * 256 + ft * 32 + tx] = T[tx][ty + i * 8];
}

// ---------------------------------------------------------------------------
// m97-style staging: (nregions*16) rows x 32 f16, row stride 32, unswizzled.
// ---------------------------------------------------------------------------
__device__ __forceinline__ void stage_rows32(const f16* __restrict__ G, int ldg,
                                             int row0, int k0, f16* S,
                                             int nregions, int w, int lane) {
#pragma unroll
    for (int rI = w; rI < nregions; rI += 4) {
        int r = rI * 16 + (lane >> 2);
        int col = (lane & 3) << 3;
        GLOAD_LDS16(G + (size_t)(row0 + r) * ldg + k0 + col, S + rI * 512);
    }
}

// ---------------------------------------------------------------------------
// 128x128 MFMA tile, BK=32. 4 waves 2x2 of 64x64.
// ---------------------------------------------------------------------------
__device__ __forceinline__ void gemm128_lds(const f16* __restrict__ A, int lda,
                                            const f16* __restrict__ Bt, int ldb,
                                            int K, f16* As, f16* Bs,
                                            f32x4 acc[4][4], int row0, int col0) {
    const int t = threadIdx.x, lane = t & 63, w = t >> 6;
    const int wr = w >> 1, wc = w & 1;
    const int lrow = lane & 15, quad = lane >> 4;
    for (int k0 = 0; k0 < K; k0 += 32) {
        __syncthreads();
        stage_rows32(A, lda, row0, k0, As, 8, w, lane);
        stage_rows32(Bt, ldb, col0, k0, Bs, 8, w, lane);
        __syncthreads();
        f16x8 af[4], bf[4];
#pragma unroll
        for (int i = 0; i < 4; ++i) {
            af[i] = *(const f16x8*)&As[(wr * 64 + i * 16 + lrow) * 32 + quad * 8];
            bf[i] = *(const f16x8*)&Bs[(wc * 64 + i * 16 + lrow) * 32 + quad * 8];
        }
#pragma unroll
        for (int i = 0; i < 4; ++i)
#pragma unroll
            for (int j = 0; j < 4; ++j)
                acc[i][j] = __builtin_amdgcn_mfma_f32_16x16x32_f16(af[i], bf[j], acc[i][j], 0, 0, 0);
    }
}

// ---------------------------------------------------------------------------
// Merged QKV projection with coalesced LDS-roundtrip epilogue.
// z=0 Q -> (b,h,s,f); z=1 K -> (b,h,s,f); z=2 V -> (b,h,f,s).
// ---------------------------------------------------------------------------
__global__ __launch_bounds__(256) void proj_mfma(const f16* __restrict__ xh,
                                                 const f16* __restrict__ wqT,
                                                 const f16* __restrict__ wkT,
                                                 const f16* __restrict__ wvT,
                                                 f16* __restrict__ qb,
                                                 f16* __restrict__ kb,
                                                 f16* __restrict__ vb) {
    const int z = blockIdx.z;
    const f16* WT = z == 0 ? wqT : (z == 1 ? wkT : wvT);
    f16* O        = z == 0 ? qb  : (z == 1 ? kb  : vb);
    __shared__ f16 smem[17408];          // As|Bs (8192) then Es (17408) alias
    f16* As = smem;
    f16* Bs = smem + 4096;
    f32x4 acc[4][4] = {};
    const int row0 = blockIdx.y * 128, col0 = blockIdx.x * 128;
    gemm128_lds(xh, FQ, WT, FQ, FQ, As, Bs, acc, row0, col0);

    __syncthreads();                     // As/Bs dead -> reuse as Es
    f16* Es = smem;                      // ld 136
    const int lane = threadIdx.x & 63, w = threadIdx.x >> 6;
    const int wr = w >> 1, wc = w & 1;
    const int lrow = lane & 15, quad = lane >> 4;
    if (z != 2) {
        // Es[row][h*16 + f_local]
#pragma unroll
        for (int i = 0; i < 4; ++i)
#pragma unroll
            for (int rr = 0; rr < 4; ++rr) {
                int rl = 64 * wr + 16 * i + 4 * quad + rr;
#pragma unroll
                for (int j = 0; j < 4; ++j) {
                    int cc = 64 * wc + 16 * j + lrow;
                    Es[rl * 136 + (cc & 7) * 16 + (cc >> 3)] = (f16)acc[i][j][rr];
                }
            }
        __syncthreads();
        const int f0 = col0 >> 3;
#pragma unroll
        for (int it = 0; it < 4; ++it) {
            int c = it * 256 + threadIdx.x;
            int row = c >> 3, hh = c & 7;
            int gr = row0 + row, bbb = gr >> 10, s = gr & 1023;
            f16x8 v0 = *(const f16x8*)&Es[row * 136 + hh * 16];
            f16x8 v1 = *(const f16x8*)&Es[row * 136 + hh * 16 + 8];
            f16* dst = O + ((size_t)(bbb * 8 + hh) * SQ + s) * FQ + f0;
            *(f16x8*)dst = v0;
            *(f16x8*)(dst + 8) = v1;
        }
    } else {
        // Es[cc][row] -> 128 s-contiguous per (h,f)
#pragma unroll
        for (int i = 0; i < 4; ++i)
#pragma unroll
            for (int rr = 0; rr < 4; ++rr) {
                int rl = 64 * wr + 16 * i + 4 * quad + rr;
#pragma unroll
                for (int j = 0; j < 4; ++j) {
                    int cc = 64 * wc + 16 * j + lrow;
                    Es[cc * 136 + rl] = (f16)acc[i][j][rr];
                }
            }
        __syncthreads();
        const int bbb = row0 >> 10, s0 = row0 & 1023;
#pragma unroll
        for (int it = 0; it < 8; ++it) {
            int c = it * 256 + threadIdx.x;
            int cc = c >> 4, sc = c & 15;
            int hh = cc & 7, f = (col0 >> 3) + (cc >> 3);
            f16x8 v = *(const f16x8*)&Es[cc * 136 + sc * 8];
            *(f16x8*)(O + ((size_t)(bbb * 8 + hh) * FQ + f) * SQ + s0 + sc * 8) = v;
        }
    }
}

// ---------------------------------------------------------------------------
// Fused attention v4 — barrier-light. Per block: 64 Q-rows of one (b,h).
//  - Q staged ONCE in swizzled LDS (reused by all 16 j-tiles).
//  - K and V fragments read DIRECTLY from global (L2): compiler emits
//    fine-grained vmcnt(N) waits, no vmcnt(0)+barrier drains in the loop.
//  - Wave mapping 1x4 (wave nw owns S-cols / f-cols slice): K, V each read
//    exactly once per block (no inter-wave duplication).
//  - Ps double-buffered -> exactly ONE __syncthreads per j-tile.
// LDS: Qs 32 KB + 2*Ps 9 KB = 50 KB -> 3 blocks/CU.
// ---------------------------------------------------------------------------
__global__ __launch_bounds__(256) void fused_attn(const f16* __restrict__ Qb,
                                                  const f16* __restrict__ Kb,
                                                  const f16* __restrict__ Vt,
                                                  f16* __restrict__ WV) {
    __shared__ f16 smem[25600];          // Qs 16384 | Ps[2] 2*4608; Es alias
    f16* Qs = smem;
    f16* Ps0 = smem + 16384;
    f16* Ps1 = smem + 16384 + 4608;
    const int t = threadIdx.x, lane = t & 63, nw = t >> 6;
    const int lrow = lane & 15, quad = lane >> 4;
    // XCD swizzle: 4 consecutive heads per XCD -> Q/K/V L2-resident per XCD.
    const int n = blockIdx.x;
    const int xcd = n & 7, rest = n >> 3;
    const int bh = xcd * 4 + (rest & 3);
    const int strip = rest >> 2;                 // 0..15
    const int m0 = strip * 64;
    const int bb = bh >> 3, h = bh & 7;
    const f16* Qg = Qb + (size_t)bh * SQ * FQ;   // (s,f)
    const f16* Kg = Kb + (size_t)bh * SQ * FQ;   // (s,f)
    const f16* Vg = Vt + (size_t)bh * FQ * SQ;   // (f,s)

    // Stage Q strip (64 x 256) once, granule-swizzled g' = g ^ (r&7).
#pragma unroll
    for (int it = 0; it < 8; ++it) {
        int c = it * 256 + t;
        int r = c >> 5, g = c & 31;
        float4 v = *(const float4*)(Qg + (size_t)(m0 + r) * FQ + (g << 3));
        *(float4*)&Qs[r * 256 + (((g ^ (r & 7)) & 31) << 3)] = v;
    }
    __syncthreads();

    f32x4 acc_o[4][4] = {};   // rows 16mi+4quad+rr, f = 64nw+16nj+lrow

    for (int jt = 0; jt < 16; ++jt) {
        const int j0 = jt * 64;
        f16* Pw = (jt & 1) ? Ps1 : Ps0;
        // ---- QK^T: S(64 x 64); wave nw owns cols 16nw..+16. K from global. ----
        f32x4 acc_s[4] = {};
#pragma unroll
        for (int ks = 0; ks < 8; ++ks) {
            f16x8 bf = *(const f16x8*)(Kg + (size_t)(j0 + 16 * nw + lrow) * FQ
                                           + ks * 32 + quad * 8);
#pragma unroll
            for (int mi = 0; mi < 4; ++mi) {
                int rq = 16 * mi + lrow;
                f16x8 af = *(const f16x8*)&Qs[rq * 256 + ((((ks * 4 + quad) ^ (rq & 7)) & 31) << 3)];
                acc_s[mi] = __builtin_amdgcn_mfma_f32_16x16x32_f16(af, bf, acc_s[mi], 0, 0, 0);
            }
        }
        // ---- sigmoid -> Ps[jt&1] (ld 72) ----
#pragma unroll
        for (int mi = 0; mi < 4; ++mi)
#pragma unroll
            for (int rr = 0; rr < 4; ++rr)
                Pw[(16 * mi + 4 * quad + rr) * 72 + 16 * nw + lrow] =
                    (f16)(1.0f / (1.0f + __expf(-16.0f * acc_s[mi][rr])));
        __syncthreads();                         // Ps visible (LDS-only dep)
        // ---- PV: WV(64 x 256) += P(64 x 64) @ V^T; wave nw owns f 64nw..+64 ----
        f16x8 ap[4][2];
#pragma unroll
        for (int mi = 0; mi < 4; ++mi)
#pragma unroll
            for (int kf = 0; kf < 2; ++kf)
                ap[mi][kf] = *(const f16x8*)&Pw[(16 * mi + lrow) * 72 + kf * 32 + quad * 8];
#pragma unroll
        for (int nj = 0; nj < 4; ++nj) {
            int f = 64 * nw + 16 * nj + lrow;
#pragma unroll
            for (int kf = 0; kf < 2; ++kf) {
                f16x8 bv = *(const f16x8*)(Vg + (size_t)f * SQ + j0 + kf * 32 + quad * 8);
#pragma unroll
                for (int mi = 0; mi < 4; ++mi)
                    acc_o[mi][nj] = __builtin_amdgcn_mfma_f32_16x16x32_f16(
                        ap[mi][kf], bv, acc_o[mi][nj], 0, 0, 0);
            }
        }
    }
    // ---- epilogue: LDS roundtrip -> 512 B contiguous rows ----
    __syncthreads();                             // Qs/Ps dead
    f16* Es = smem;                              // 64 x 264
#pragma unroll
    for (int mi = 0; mi < 4; ++mi)
#pragma unroll
        for (int nj = 0; nj < 4; ++nj)
#pragma unroll
            for (int rr = 0; rr < 4; ++rr)
                Es[(16 * mi + 4 * quad + rr) * 264 + 64 * nw + 16 * nj + lrow] =
                    (f16)acc_o[mi][nj][rr];
    __syncthreads();
#pragma unroll
    for (int it = 0; it < 8; ++it) {
        int c = it * 256 + t;
        int r = c >> 5, ck = c & 31;
        f16x8 v = *(const f16x8*)&Es[r * 264 + ck * 8];
        *(f16x8*)(WV + (size_t)(bb * SQ + m0 + r) * FH + h * 256 + ck * 8) = v;
    }
}

// ---------------------------------------------------------------------------
// out projection, split-K x2 over k = h*256+f. 64x64 tiles, grid (4, 64, 2).
// ---------------------------------------------------------------------------
__global__ __launch_bounds__(256) void out_split(const f16* __restrict__ WVm,
                                                 const f16* __restrict__ WoT,
                                                 float* __restrict__ PP) {
    __shared__ f16 As[64 * 32];
    __shared__ f16 Bs[64 * 32];
    const int t = threadIdx.x, lane = t & 63, w = t >> 6;
    const int wr = w >> 1, wc = w & 1;
    const int lrow = lane & 15, quad = lane >> 4;
    const int row0 = blockIdx.y * 64, col0 = blockIdx.x * 64;
    const int kbase = blockIdx.z * 1024;
    f32x4 acc[2][2] = {};
    for (int k0 = 0; k0 < 1024; k0 += 32) {
        __syncthreads();
        stage_rows32(WVm, FH, row0, kbase + k0, As, 4, w, lane);
        stage_rows32(WoT, FH, col0, kbase + k0, Bs, 4, w, lane);
        __syncthreads();
        f16x8 af[2], bf[2];
#pragma unroll
        for (int i = 0; i < 2; ++i) {
            af[i] = *(const f16x8*)&As[(wr * 32 + i * 16 + lrow) * 32 + quad * 8];
            bf[i] = *(const f16x8*)&Bs[(wc * 32 + i * 16 + lrow) * 32 + quad * 8];
        }
#pragma unroll
        for (int i = 0; i < 2; ++i)
#pragma unroll
            for (int j = 0; j < 2; ++j)
                acc[i][j] = __builtin_amdgcn_mfma_f32_16x16x32_f16(af[i], bf[j], acc[i][j], 0, 0, 0);
    }
    float* P = PP + (size_t)blockIdx.z * SQ * 4 * FQ;
#pragma unroll
    for (int i = 0; i < 2; ++i)
#pragma unroll
        for (int r = 0; r < 4; ++r) {
            int gr = row0 + wr * 32 + i * 16 + quad * 4 + r;
#pragma unroll
            for (int j = 0; j < 2; ++j) {
                int gc = col0 + wc * 32 + j * 16 + lrow;
                P[(size_t)gr * FQ + gc] = acc[i][j][r];
            }
        }
}

__global__ __launch_bounds__(256) void reduce_relu(const float* __restrict__ PP,
                                                   float* __restrict__ O) {
    int idx = (blockIdx.x * 256 + threadIdx.x) * 4;
    f32x4 a = *(const f32x4*)(PP + idx);
    f32x4 b = *(const f32x4*)(PP + 1048576 + idx);
    f32x4 s = a + b;
    f32x4 r = {fmaxf(s.x, 0.f), fmaxf(s.y, 0.f), fmaxf(s.z, 0.f), fmaxf(s.w, 0.f)};
    *(f32x4*)(O + idx) = r;
}

// ---------------------------------------------------------------------------
extern "C" void kernel_launch(void* const* d_in, const int* in_sizes, int n_in,
                              void* d_out, int out_size, void* d_ws, size_t ws_size,
                              hipStream_t stream) {
    const float* x  = (const float*)d_in[0];
    const float* Wq = (const float*)d_in[1];
    const float* Wk = (const float*)d_in[2];
    const float* Wv = (const float*)d_in[3];
    const float* Wo = (const float*)d_in[4];
    float* out = (float*)d_out;

    f16* ws = (f16*)d_ws;
    f16* xh    = ws;                       // 1,048,576
    f16* wqT   = xh    + 1048576;          // 524,288
    f16* wkT   = wqT   + 524288;
    f16* wvT   = wkT   + 524288;
    f16* woT   = wvT   + 524288;           // 524,288 (k permuted to h*256+f)
    f16* qbuf  = woT   + 524288;           // 8,388,608 (b,h,s,f)
    f16* kbuf  = qbuf  + 8388608;          // (b,h,s,f)
    f16* vbuf  = kbuf  + 8388608;          // (b,h,f,s)
    f16* wvbuf = vbuf  + 8388608;          // (b*s, h*256+f)
    float* pp  = (float*)(wvbuf + 8388608);// 2 x 1,048,576 fp32 partials

    dim3 blk(256);
    cvt_kernel<<<dim3(1024), blk, 0, stream>>>(x, xh);
    transpose_qkv<<<dim3(64, 8, 3), blk, 0, stream>>>(Wq, Wk, Wv, wqT, wkT, wvT);
    transpose_wo<<<dim3(8, 64), blk, 0, stream>>>(Wo, woT);

    proj_mfma<<<dim3(16, 32, 3), blk, 0, stream>>>(xh, wqT, wkT, wvT, qbuf, kbuf, vbuf);

    fused_attn<<<dim3(512), blk, 0, stream>>>(qbuf, kbuf, vbuf, wvbuf);

    out_split<<<dim3(4, 64, 2), blk, 0, stream>>>(wvbuf, woT, pp);
    reduce_relu<<<dim3(1024), blk, 0, stream>>>(pp, out);
}

// Round 8
// 212.311 us; speedup vs baseline: 1.0324x; 1.0324x over previous
//
#include <hip/hip_runtime.h>
#include <math.h>

// Problem: B=4, S=1024, F=256, H=8, FH=2048. SCALE=16 (multiplies logits).
#define SQ 1024
#define FQ 256
#define FH 2048

typedef _Float16 f16;
typedef f16  f16x8 __attribute__((ext_vector_type(8)));
typedef float f32x4 __attribute__((ext_vector_type(4)));

// Async global->LDS, 16 B/lane. LDS dest = wave-uniform base + lane*16.
#define GLOAD_LDS16(gp, lp) \
    __builtin_amdgcn_global_load_lds((const __attribute__((address_space(1))) void*)(gp), \
                                     (__attribute__((address_space(3))) void*)(lp), 16, 0, 0)

// ---------------------------------------------------------------------------
// fp32 -> f16 convert (x input).
// ---------------------------------------------------------------------------
__global__ __launch_bounds__(256) void cvt_kernel(const float* __restrict__ in,
                                                  f16* __restrict__ out) {
    int idx = (blockIdx.x * 256 + threadIdx.x) * 4;
    float4 v = *(const float4*)(in + idx);
    out[idx + 0] = (f16)v.x; out[idx + 1] = (f16)v.y;
    out[idx + 2] = (f16)v.z; out[idx + 3] = (f16)v.w;
}

// ---------------------------------------------------------------------------
// Transpose+convert W (256 x 2048 fp32) -> WT (2048 x 256 f16). z picks matrix.
// ---------------------------------------------------------------------------
__global__ __launch_bounds__(256) void transpose_qkv(const float* __restrict__ W0,
                                                     const float* __restrict__ W1,
                                                     const float* __restrict__ W2,
                                                     f16* __restrict__ T0,
                                                     f16* __restrict__ T1,
                                                     f16* __restrict__ T2) {
    const float* W = blockIdx.z == 0 ? W0 : (blockIdx.z == 1 ? W1 : W2);
    f16* WT        = blockIdx.z == 0 ? T0 : (blockIdx.z == 1 ? T1 : T2);
    __shared__ f16 T[32][33];
    const int tx = threadIdx.x & 31, ty = threadIdx.x >> 5;
    const int n0 = blockIdx.x * 32, k0 = blockIdx.y * 32;
#pragma unroll
    for (int i = 0; i < 4; ++i)
        T[ty + i * 8][tx] = (f16)W[(size_t)(k0 + ty + i * 8) * FH + n0 + tx];
    __syncthreads();
#pragma unroll
    for (int i = 0; i < 4; ++i)
        WT[(size_t)(n0 + ty + i * 8) * FQ + k0 + tx] = T[tx][ty + i * 8];
}

// ---------------------------------------------------------------------------
// Wo (2048 x 256 fp32, row fh = f*8+h) -> WoT (256 x 2048 f16) with k
// PERMUTED to h*256+f (matches WV layout). grid (8 n-tiles, 64 = ft*8+h).
// ---------------------------------------------------------------------------
__global__ __launch_bounds__(256) void transpose_wo(const float* __restrict__ W,
                                                    f16* __restrict__ WT) {
    __shared__ f16 T[32][33];
    const int tx = threadIdx.x & 31, ty = threadIdx.x >> 5;
    const int n0 = blockIdx.x * 32;
    const int ft = blockIdx.y >> 3, h = blockIdx.y & 7;
#pragma unroll
    for (int i = 0; i < 4; ++i) {
        int fl = ty + i * 8;
        T[fl][tx] = (f16)W[(size_t)((ft * 32 + fl) * 8 + h) * FQ + n0 + tx];
    }
    __syncthreads();
#pragma unroll
    for (int i = 0; i < 4; ++i)
        WT[(size_t)(n0 + ty + i * 8) * FH + h * 256 + ft * 32 + tx] = T[tx][ty + i * 8];
}

// ---------------------------------------------------------------------------
// Swizzled staging, LDS row stride 64 f16 (128 B): 8 rows/inst, logical
// granule g (0..7) stored at physical slot g^(row&7). Read back with
//   &S[r*64 + ((g ^ (r&7)) << 3)]
// ---------------------------------------------------------------------------
__device__ __forceinline__ void stage_sw64(const f16* __restrict__ G, int ldg,
                                           int row0, int c0, f16* S,
                                           int nrows, int w, int lane) {
    const int rsub = lane >> 3;           // 0..7
    const int g    = (lane & 7) ^ (rsub & 7);
#pragma unroll
    for (int rI = w; rI < (nrows >> 3); rI += 4) {
        GLOAD_LDS16(G + (size_t)(row0 + rI * 8 + rsub) * ldg + c0 + g * 8,
                    S + rI * 512);
    }
}

// ---------------------------------------------------------------------------
// 128x128 MFMA tile, BK=64 swizzled staging. 4 waves 2x2 of 64x64.
// A: [M][K] row-major; Bt: [N][K] row-major. K range [kbeg, kend).
// 32 MFMA/wave per barrier-drain pair.
// ---------------------------------------------------------------------------
__device__ __forceinline__ void gemm128_sw(const f16* __restrict__ A, int lda,
                                           const f16* __restrict__ Bt, int ldb,
                                           int kbeg, int kend, f16* As, f16* Bs,
                                           f32x4 acc[4][4], int row0, int col0) {
    const int t = threadIdx.x, lane = t & 63, w = t >> 6;
    const int wr = w >> 1, wc = w & 1;
    const int lrow = lane & 15, quad = lane >> 4;
    for (int k0 = kbeg; k0 < kend; k0 += 64) {
        __syncthreads();
        stage_sw64(A, lda, row0, k0, As, 128, w, lane);
        stage_sw64(Bt, ldb, col0, k0, Bs, 128, w, lane);
        __syncthreads();
#pragma unroll
        for (int kk = 0; kk < 2; ++kk) {
            f16x8 af[4], bf[4];
#pragma unroll
            for (int i = 0; i < 4; ++i) {
                int r = wr * 64 + i * 16 + lrow;
                af[i] = *(const f16x8*)&As[r * 64 + (((kk * 4 + quad) ^ (r & 7)) << 3)];
            }
#pragma unroll
            for (int j = 0; j < 4; ++j) {
                int r = wc * 64 + j * 16 + lrow;
                bf[j] = *(const f16x8*)&Bs[r * 64 + (((kk * 4 + quad) ^ (r & 7)) << 3)];
            }
#pragma unroll
            for (int i = 0; i < 4; ++i)
#pragma unroll
                for (int j = 0; j < 4; ++j)
                    acc[i][j] = __builtin_amdgcn_mfma_f32_16x16x32_f16(af[i], bf[j], acc[i][j], 0, 0, 0);
        }
    }
}

// ---------------------------------------------------------------------------
// Merged QKV projection with coalesced LDS-roundtrip epilogue.
// z=0 Q -> (b,h,s,f); z=1 K -> (b,h,s,f); z=2 V -> (b,h,f,s).
// ---------------------------------------------------------------------------
__global__ __launch_bounds__(256) void proj_mfma(const f16* __restrict__ xh,
                                                 const f16* __restrict__ wqT,
                                                 const f16* __restrict__ wkT,
                                                 const f16* __restrict__ wvT,
                                                 f16* __restrict__ qb,
                                                 f16* __restrict__ kb,
                                                 f16* __restrict__ vb) {
    const int z = blockIdx.z;
    const f16* WT = z == 0 ? wqT : (z == 1 ? wkT : wvT);
    f16* O        = z == 0 ? qb  : (z == 1 ? kb  : vb);
    __shared__ f16 smem[17408];          // As|Bs (16384) ; Es (17408) alias
    f16* As = smem;
    f16* Bs = smem + 8192;
    f32x4 acc[4][4] = {};
    const int row0 = blockIdx.y * 128, col0 = blockIdx.x * 128;
    gemm128_sw(xh, FQ, WT, FQ, 0, FQ, As, Bs, acc, row0, col0);

    __syncthreads();                     // As/Bs dead -> reuse as Es
    f16* Es = smem;                      // ld 136
    const int lane = threadIdx.x & 63, w = threadIdx.x >> 6;
    const int wr = w >> 1, wc = w & 1;
    const int lrow = lane & 15, quad = lane >> 4;
    if (z != 2) {
        // Es[row][h*16 + f_local]
#pragma unroll
        for (int i = 0; i < 4; ++i)
#pragma unroll
            for (int rr = 0; rr < 4; ++rr) {
                int rl = 64 * wr + 16 * i + 4 * quad + rr;
#pragma unroll
                for (int j = 0; j < 4; ++j) {
                    int cc = 64 * wc + 16 * j + lrow;
                    Es[rl * 136 + (cc & 7) * 16 + (cc >> 3)] = (f16)acc[i][j][rr];
                }
            }
        __syncthreads();
        const int f0 = col0 >> 3;
#pragma unroll
        for (int it = 0; it < 4; ++it) {
            int c = it * 256 + threadIdx.x;
            int row = c >> 3, hh = c & 7;
            int gr = row0 + row, bbb = gr >> 10, s = gr & 1023;
            f16x8 v0 = *(const f16x8*)&Es[row * 136 + hh * 16];
            f16x8 v1 = *(const f16x8*)&Es[row * 136 + hh * 16 + 8];
            f16* dst = O + ((size_t)(bbb * 8 + hh) * SQ + s) * FQ + f0;
            *(f16x8*)dst = v0;
            *(f16x8*)(dst + 8) = v1;
        }
    } else {
        // Es[cc][row] -> 128 s-contiguous per (h,f)
#pragma unroll
        for (int i = 0; i < 4; ++i)
#pragma unroll
            for (int rr = 0; rr < 4; ++rr) {
                int rl = 64 * wr + 16 * i + 4 * quad + rr;
#pragma unroll
                for (int j = 0; j < 4; ++j) {
                    int cc = 64 * wc + 16 * j + lrow;
                    Es[cc * 136 + rl] = (f16)acc[i][j][rr];
                }
            }
        __syncthreads();
        const int bbb = row0 >> 10, s0 = row0 & 1023;
#pragma unroll
        for (int it = 0; it < 8; ++it) {
            int c = it * 256 + threadIdx.x;
            int cc = c >> 4, sc = c & 15;
            int hh = cc & 7, f = (col0 >> 3) + (cc >> 3);
            f16x8 v = *(const f16x8*)&Es[cc * 136 + sc * 8];
            *(f16x8*)(O + ((size_t)(bbb * 8 + hh) * FQ + f) * SQ + s0 + sc * 8) = v;
        }
    }
}

// ---------------------------------------------------------------------------
// Fused attention v5 — register-pipelined K/V. Per block: 64 Q-rows of (b,h).
//  - Q staged once in swizzled LDS (reused by all 16 j-tiles).
//  - K frags double-buffered in REGISTERS: kn (tile jt+1) + vc (tile jt)
//    issued at iteration top; QK+sigmoid (~700 cyc) hides their L2 latency;
//    the single mid-iteration barrier drains already-complete loads.
//  - Wave nw owns S-cols [16nw,16nw+16) in QK, f-cols [64nw,64nw+64) in PV.
// LDS: Qs 32 KB + 2x Ps 9 KB = 50 KB. VGPR ~210 by design.
// ---------------------------------------------------------------------------
__global__ __launch_bounds__(256) void fused_attn(const f16* __restrict__ Qb,
                                                  const f16* __restrict__ Kb,
                                                  const f16* __restrict__ Vt,
                                                  f16* __restrict__ WV) {
    __shared__ f16 smem[25600];          // Qs 16384 | Ps[2] 2*4608; Es alias
    f16* Qs = smem;
    f16* Ps0 = smem + 16384;
    f16* Ps1 = smem + 16384 + 4608;
    const int t = threadIdx.x, lane = t & 63, nw = t >> 6;
    const int lrow = lane & 15, quad = lane >> 4;
    // XCD swizzle: 4 consecutive heads per XCD -> Q/K/V L2-resident per XCD.
    const int n = blockIdx.x;
    const int xcd = n & 7, rest = n >> 3;
    const int bh = xcd * 4 + (rest & 3);
    const int strip = rest >> 2;                 // 0..15
    const int m0 = strip * 64;
    const int bb = bh >> 3, h = bh & 7;
    const f16* Qg = Qb + (size_t)bh * SQ * FQ;   // (s,f)
    const f16* Kg = Kb + (size_t)bh * SQ * FQ;   // (s,f)
    const f16* Vg = Vt + (size_t)bh * FQ * SQ;   // (f,s)

    // Stage Q strip (64 x 256) once, granule-swizzled g' = g ^ (r&7).
#pragma unroll
    for (int it = 0; it < 8; ++it) {
        int c = it * 256 + t;
        int r = c >> 5, g = c & 31;
        float4 v = *(const float4*)(Qg + (size_t)(m0 + r) * FQ + (g << 3));
        *(float4*)&Qs[r * 256 + (((g ^ (r & 7)) & 31) << 3)] = v;
    }
    __syncthreads();

    const f16* Kbase = Kg + (size_t)(16 * nw + lrow) * FQ + quad * 8;
    const f16* Vbase = Vg + (size_t)(64 * nw + lrow) * SQ + quad * 8;

    f32x4 acc_o[4][4] = {};   // rows 16mi+4quad+rr, f = 64nw+16nj+lrow
    f16x8 kc[8], vc[8];
    // prefetch K tile 0
#pragma unroll
    for (int ks = 0; ks < 8; ++ks)
        kc[ks] = *(const f16x8*)(Kbase + ks * 32);

    for (int jt = 0; jt < 16; ++jt) {
        const int j0 = jt * 64;
        f16* Pw = (jt & 1) ? Ps1 : Ps0;
        // ---- issue V(current) + K(next) loads; consumed after ~700 cyc ----
#pragma unroll
        for (int i = 0; i < 8; ++i)
            vc[i] = *(const f16x8*)(Vbase + (size_t)((i >> 1) * 16) * SQ
                                          + j0 + (i & 1) * 32);
        f16x8 kn[8];
        if (jt < 15) {
#pragma unroll
            for (int ks = 0; ks < 8; ++ks)
                kn[ks] = *(const f16x8*)(Kbase + (size_t)(j0 + 64) * FQ + ks * 32);
        }
        // ---- QK^T from resident kc: S(64x64), wave nw owns cols 16nw..+16 ----
        f32x4 acc_s[4] = {};
#pragma unroll
        for (int ks = 0; ks < 8; ++ks) {
#pragma unroll
            for (int mi = 0; mi < 4; ++mi) {
                int rq = 16 * mi + lrow;
                f16x8 af = *(const f16x8*)&Qs[rq * 256 + ((((ks * 4 + quad) ^ (rq & 7)) & 31) << 3)];
                acc_s[mi] = __builtin_amdgcn_mfma_f32_16x16x32_f16(af, kc[ks], acc_s[mi], 0, 0, 0);
            }
        }
        // ---- sigmoid -> Ps[jt&1] (ld 72) ----
#pragma unroll
        for (int mi = 0; mi < 4; ++mi)
#pragma unroll
            for (int rr = 0; rr < 4; ++rr)
                Pw[(16 * mi + 4 * quad + rr) * 72 + 16 * nw + lrow] =
                    (f16)(1.0f / (1.0f + __expf(-16.0f * acc_s[mi][rr])));
        __syncthreads();     // Ps visible; drains kn/vc (already complete)
        // ---- PV: WV(64x256) += P(64x64) @ V^T from resident vc ----
        f16x8 ap[4][2];
#pragma unroll
        for (int mi = 0; mi < 4; ++mi)
#pragma unroll
            for (int kf = 0; kf < 2; ++kf)
                ap[mi][kf] = *(const f16x8*)&Pw[(16 * mi + lrow) * 72 + kf * 32 + quad * 8];
#pragma unroll
        for (int nj = 0; nj < 4; ++nj)
#pragma unroll
            for (int kf = 0; kf < 2; ++kf)
#pragma unroll
                for (int mi = 0; mi < 4; ++mi)
                    acc_o[mi][nj] = __builtin_amdgcn_mfma_f32_16x16x32_f16(
                        ap[mi][kf], vc[nj * 2 + kf], acc_o[mi][nj], 0, 0, 0);
        // ---- rotate K double-buffer ----
        if (jt < 15) {
#pragma unroll
            for (int ks = 0; ks < 8; ++ks) kc[ks] = kn[ks];
        }
    }
    // ---- epilogue: LDS roundtrip -> 512 B contiguous rows ----
    __syncthreads();                             // Qs/Ps dead
    f16* Es = smem;                              // 64 x 264
#pragma unroll
    for (int mi = 0; mi < 4; ++mi)
#pragma unroll
        for (int nj = 0; nj < 4; ++nj)
#pragma unroll
            for (int rr = 0; rr < 4; ++rr)
                Es[(16 * mi + 4 * quad + rr) * 264 + 64 * nw + 16 * nj + lrow] =
                    (f16)acc_o[mi][nj][rr];
    __syncthreads();
#pragma unroll
    for (int it = 0; it < 8; ++it) {
        int c = it * 256 + t;
        int r = c >> 5, ck = c & 31;
        f16x8 v = *(const f16x8*)&Es[r * 264 + ck * 8];
        *(f16x8*)(WV + (size_t)(bb * SQ + m0 + r) * FH + h * 256 + ck * 8) = v;
    }
}

// ---------------------------------------------------------------------------
// out projection, split-K x8 over k = h*256+f. 128x128 tiles, grid (2,32,8).
// 8 iters x 32 MFMA/wave per drain pair. fp32 partials (ALIASED onto dead
// qbuf/kbuf workspace -- exactly 32 MB -- to stay inside d_ws).
// ---------------------------------------------------------------------------
__global__ __launch_bounds__(256) void out_mfma8(const f16* __restrict__ WVm,
                                                 const f16* __restrict__ WoT,
                                                 float* __restrict__ PP) {
    __shared__ f16 smem[16384];
    f16* As = smem;
    f16* Bs = smem + 8192;
    f32x4 acc[4][4] = {};
    const int row0 = blockIdx.y * 128, col0 = blockIdx.x * 128;
    const int kbeg = blockIdx.z * 256;
    gemm128_sw(WVm, FH, WoT, FH, kbeg, kbeg + 256, As, Bs, acc, row0, col0);

    float* P = PP + (size_t)blockIdx.z * SQ * 4 * FQ;
    const int lane = threadIdx.x & 63, w = threadIdx.x >> 6;
    const int wr = w >> 1, wc = w & 1;
    const int lrow = lane & 15, quad = lane >> 4;
#pragma unroll
    for (int i = 0; i < 4; ++i)
#pragma unroll
        for (int rr = 0; rr < 4; ++rr) {
            int gr = row0 + wr * 64 + i * 16 + quad * 4 + rr;
#pragma unroll
            for (int j = 0; j < 4; ++j) {
                int gc = col0 + wc * 64 + j * 16 + lrow;
                P[(size_t)gr * FQ + gc] = acc[i][j][rr];
            }
        }
}

__global__ __launch_bounds__(256) void reduce_relu8(const float* __restrict__ PP,
                                                    float* __restrict__ O) {
    int idx = (blockIdx.x * 256 + threadIdx.x) * 4;
    f32x4 s = *(const f32x4*)(PP + idx);
#pragma unroll
    for (int z = 1; z < 8; ++z)
        s += *(const f32x4*)(PP + (size_t)z * 1048576 + idx);
    f32x4 r = {fmaxf(s.x, 0.f), fmaxf(s.y, 0.f), fmaxf(s.z, 0.f), fmaxf(s.w, 0.f)};
    *(f32x4*)(O + idx) = r;
}

// ---------------------------------------------------------------------------
extern "C" void kernel_launch(void* const* d_in, const int* in_sizes, int n_in,
                              void* d_out, int out_size, void* d_ws, size_t ws_size,
                              hipStream_t stream) {
    const float* x  = (const float*)d_in[0];
    const float* Wq = (const float*)d_in[1];
    const float* Wk = (const float*)d_in[2];
    const float* Wv = (const float*)d_in[3];
    const float* Wo = (const float*)d_in[4];
    float* out = (float*)d_out;

    f16* ws = (f16*)d_ws;
    f16* xh    = ws;                       // 1,048,576
    f16* wqT   = xh    + 1048576;          // 524,288
    f16* wkT   = wqT   + 524288;
    f16* wvT   = wkT   + 524288;
    f16* woT   = wvT   + 524288;           // 524,288 (k permuted to h*256+f)
    f16* qbuf  = woT   + 524288;           // 8,388,608 (b,h,s,f)
    f16* kbuf  = qbuf  + 8388608;          // (b,h,s,f)
    f16* vbuf  = kbuf  + 8388608;          // (b,h,f,s)
    f16* wvbuf = vbuf  + 8388608;          // (b*s, h*256+f)
    // pp ALIASES qbuf+kbuf (dead after fused_attn): 8 x 1,048,576 fp32 = 32 MB.
    // Total d_ws footprint stays ~70 MB (round-6-proven size) -- no OOB.
    float* pp  = (float*)qbuf;

    dim3 blk(256);
    cvt_kernel<<<dim3(1024), blk, 0, stream>>>(x, xh);
    transpose_qkv<<<dim3(64, 8, 3), blk, 0, stream>>>(Wq, Wk, Wv, wqT, wkT, wvT);
    transpose_wo<<<dim3(8, 64), blk, 0, stream>>>(Wo, woT);

    proj_mfma<<<dim3(16, 32, 3), blk, 0, stream>>>(xh, wqT, wkT, wvT, qbuf, kbuf, vbuf);

    fused_attn<<<dim3(512), blk, 0, stream>>>(qbuf, kbuf, vbuf, wvbuf);

    out_mfma8<<<dim3(2, 32, 8), blk, 0, stream>>>(wvbuf, woT, pp);
    reduce_relu8<<<dim3(1024), blk, 0, stream>>>(pp, out);
}